// Round 1
// baseline (23.660 us; speedup 1.0000x reference)
//
#include <hip/hip_runtime.h>
#include <math.h>

// Key insight: reference output = relu(relu(h2[t=6]) @ W_lin^T + b_lin).
// Only timesteps 0..6 of the 512-step 2-layer LSTM affect the output.
// So: run 7 fused LSTM steps (2 layers) and the linear head, all fp32.
//
// Decomposition:
//   gate phase : thread = (gate_row g in [0,80), batch_quad bq in [0,4))
//                weights for row g held in REGISTERS (83 VGPRs), inputs read
//                as float4 from transposed LDS tiles (broadcast reads).
//   update phase: thread = (batch b in [0,16), unit u in [0,20));
//                c1/c2 state lives in that thread's registers for all 7 steps.
// Block = 320 threads = 80*4 = 16*20, batch tile 16, grid = B/16 = 256 blocks.

constexpr int kT  = 7;    // timesteps that matter
constexpr int kI  = 23;   // input dim
constexpr int kH  = 20;   // hidden dim
constexpr int kG  = 80;   // 4*H gate rows
constexpr int kBT = 16;   // batch tile per block
constexpr int kThreads = 320;

__device__ __forceinline__ float sigm(float v) {
    return 1.0f / (1.0f + __expf(-v));
}
__device__ __forceinline__ float tanh_(float v) {
    // 1 - 2/(exp(2v)+1): exact limits at +/-inf, no inf/inf NaN
    float e = __expf(2.0f * v);
    return 1.0f - 2.0f / (e + 1.0f);
}

__global__ __launch_bounds__(kThreads) void lstm7_kernel(
    const float* __restrict__ x,
    const float* __restrict__ h0,
    const float* __restrict__ c0,
    const float* __restrict__ Wih0,
    const float* __restrict__ Whh0,
    const float* __restrict__ bih0,
    const float* __restrict__ bhh0,
    const float* __restrict__ Wih1,
    const float* __restrict__ Whh1,
    const float* __restrict__ bih1,
    const float* __restrict__ bhh1,
    const float* __restrict__ Wlin,
    const float* __restrict__ blin,
    float* __restrict__ out,
    int B)
{
    // transposed tiles: [..][b] with row stride kH(=20 floats, 80B) so that
    // float4 reads at b=0,4,8,12 are 16B-aligned. Batch entries 16..19 pad.
    __shared__ __align__(16) float xT[kT][kI][kH];  // [t][i][b]
    __shared__ __align__(16) float gT[kG][kH];      // [gate_row][b]
    __shared__ __align__(16) float h1T[kH][kH];     // [unit][b]
    __shared__ __align__(16) float h2T[kH][kH];     // [unit][b]

    const int tid = threadIdx.x;
    const int b0  = blockIdx.x * kBT;

    // ---- preload x tile (transposed) for t = 0..6 ----
    for (int idx = tid; idx < kT * kBT * kI; idx += kThreads) {
        int t = idx / (kBT * kI);
        int r = idx % (kBT * kI);
        int b = r / kI;
        int i = r % kI;
        xT[t][i][b] = x[((size_t)t * B + (b0 + b)) * kI + i];
    }

    // ---- gate-phase identity: row g, batches 4*bq .. 4*bq+3 ----
    const int g  = tid % kG;
    const int bq = tid / kG;  // 0..3

    // weights for this gate row -> registers (fully unrolled, static indices)
    float wA[kI], wB[kH], wC[kH], wD[kH];
#pragma unroll
    for (int k = 0; k < kI; ++k) wA[k] = Wih0[g * kI + k];
#pragma unroll
    for (int k = 0; k < kH; ++k) wB[k] = Whh0[g * kH + k];
#pragma unroll
    for (int k = 0; k < kH; ++k) wC[k] = Wih1[g * kH + k];
#pragma unroll
    for (int k = 0; k < kH; ++k) wD[k] = Whh1[g * kH + k];
    const float bias1 = bih0[g] + bhh0[g];
    const float bias2 = bih1[g] + bhh1[g];

    // ---- update-phase identity: (batch pb, unit pu); state in registers ----
    const int pb = tid / kH;  // 0..15
    const int pu = tid % kH;  // 0..19
    float c1 = c0[(size_t)0 * B * kH + (size_t)(b0 + pb) * kH + pu];
    float c2 = c0[(size_t)1 * B * kH + (size_t)(b0 + pb) * kH + pu];
    h1T[pu][pb] = h0[(size_t)0 * B * kH + (size_t)(b0 + pb) * kH + pu];
    h2T[pu][pb] = h0[(size_t)1 * B * kH + (size_t)(b0 + pb) * kH + pu];

    __syncthreads();

    for (int t = 0; t < kT; ++t) {
        // ================= layer 1 gates =================
        float a0 = bias1, a1 = bias1, a2 = bias1, a3 = bias1;
#pragma unroll
        for (int k = 0; k < kI; ++k) {
            const float4 v = *reinterpret_cast<const float4*>(&xT[t][k][bq * 4]);
            a0 = fmaf(wA[k], v.x, a0);
            a1 = fmaf(wA[k], v.y, a1);
            a2 = fmaf(wA[k], v.z, a2);
            a3 = fmaf(wA[k], v.w, a3);
        }
#pragma unroll
        for (int k = 0; k < kH; ++k) {
            const float4 v = *reinterpret_cast<const float4*>(&h1T[k][bq * 4]);
            a0 = fmaf(wB[k], v.x, a0);
            a1 = fmaf(wB[k], v.y, a1);
            a2 = fmaf(wB[k], v.z, a2);
            a3 = fmaf(wB[k], v.w, a3);
        }
        *reinterpret_cast<float4*>(&gT[g][bq * 4]) = make_float4(a0, a1, a2, a3);
        __syncthreads();

        // ================= layer 1 update =================
        {
            const float gi = gT[pu][pb];
            const float gf = gT[kH + pu][pb];
            const float gc = gT[2 * kH + pu][pb];
            const float go = gT[3 * kH + pu][pb];
            c1 = sigm(gf) * c1 + sigm(gi) * tanh_(gc);
            h1T[pu][pb] = sigm(go) * tanh_(c1);
        }
        __syncthreads();

        // ================= layer 2 gates =================
        a0 = bias2; a1 = bias2; a2 = bias2; a3 = bias2;
#pragma unroll
        for (int k = 0; k < kH; ++k) {
            const float4 v = *reinterpret_cast<const float4*>(&h1T[k][bq * 4]);
            a0 = fmaf(wC[k], v.x, a0);
            a1 = fmaf(wC[k], v.y, a1);
            a2 = fmaf(wC[k], v.z, a2);
            a3 = fmaf(wC[k], v.w, a3);
        }
#pragma unroll
        for (int k = 0; k < kH; ++k) {
            const float4 v = *reinterpret_cast<const float4*>(&h2T[k][bq * 4]);
            a0 = fmaf(wD[k], v.x, a0);
            a1 = fmaf(wD[k], v.y, a1);
            a2 = fmaf(wD[k], v.z, a2);
            a3 = fmaf(wD[k], v.w, a3);
        }
        *reinterpret_cast<float4*>(&gT[g][bq * 4]) = make_float4(a0, a1, a2, a3);
        __syncthreads();

        // ================= layer 2 update =================
        {
            const float gi = gT[pu][pb];
            const float gf = gT[kH + pu][pb];
            const float gc = gT[2 * kH + pu][pb];
            const float go = gT[3 * kH + pu][pb];
            c2 = sigm(gf) * c2 + sigm(gi) * tanh_(gc);
            h2T[pu][pb] = sigm(go) * tanh_(c2);
        }
        __syncthreads();
    }

    // ---- linear head on t = 6: out[b] = relu(relu(h2).Wlin + blin) ----
    if (tid < kBT) {
        const int b = tid;
        float acc = blin[0];
#pragma unroll
        for (int u = 0; u < kH; ++u) {
            acc = fmaf(fmaxf(h2T[u][b], 0.0f), Wlin[u], acc);
        }
        out[b0 + b] = fmaxf(acc, 0.0f);
    }
}

extern "C" void kernel_launch(void* const* d_in, const int* in_sizes, int n_in,
                              void* d_out, int out_size, void* d_ws, size_t ws_size,
                              hipStream_t stream) {
    const float* x    = (const float*)d_in[0];
    const float* h0   = (const float*)d_in[1];
    const float* c0   = (const float*)d_in[2];
    const float* Wih0 = (const float*)d_in[3];
    const float* Whh0 = (const float*)d_in[4];
    const float* bih0 = (const float*)d_in[5];
    const float* bhh0 = (const float*)d_in[6];
    const float* Wih1 = (const float*)d_in[7];
    const float* Whh1 = (const float*)d_in[8];
    const float* bih1 = (const float*)d_in[9];
    const float* bhh1 = (const float*)d_in[10];
    const float* Wlin = (const float*)d_in[11];
    const float* blin = (const float*)d_in[12];
    float* out = (float*)d_out;

    const int B = in_sizes[1] / (2 * kH);  // h0 is [L=2, B, H=20]
    const int blocks = B / kBT;            // 4096/16 = 256

    hipLaunchKernelGGL(lstm7_kernel, dim3(blocks), dim3(kThreads), 0, stream,
                       x, h0, c0, Wih0, Whh0, bih0, bhh0,
                       Wih1, Whh1, bih1, bhh1, Wlin, blin, out, B);
}